// Round 1
// baseline (150.456 us; speedup 1.0000x reference)
//
#include <hip/hip_runtime.h>
#include <math.h>

#define DIM 512
#define HID 8
#define LN_EPS 1e-5f

__device__ __forceinline__ float gelu_exact(float v) {
    return 0.5f * v * (1.0f + erff(v * 0.70710678118654752440f));
}

__device__ __forceinline__ void load8(float* dst, const float* __restrict__ src) {
    const float4* p = reinterpret_cast<const float4*>(src);
    float4 a = p[0];
    float4 b = p[1];
    dst[0] = a.x; dst[1] = a.y; dst[2] = a.z; dst[3] = a.w;
    dst[4] = b.x; dst[5] = b.y; dst[6] = b.z; dst[7] = b.w;
}

__global__ __launch_bounds__(256, 2)
void mlp_fused_kernel(const float* __restrict__ x,
                      const float* __restrict__ w1,
                      const float* __restrict__ b1,
                      const float* __restrict__ w2,
                      const float* __restrict__ b2,
                      const float* __restrict__ gamma,
                      const float* __restrict__ beta,
                      float* __restrict__ out,
                      int nrows, int rows_per_wave) {
    const int lane  = threadIdx.x & 63;
    const int widx  = threadIdx.x >> 6;
    const int wgid  = blockIdx.x * 4 + widx;
    const int dbase = lane * 8;              // this lane owns d = dbase..dbase+7

    const int r0 = wgid * rows_per_wave;
    if (r0 >= nrows) return;
    int r1 = r0 + rows_per_wave;
    if (r1 > nrows) r1 = nrows;

    // ---- hoist all weights/params into registers (row-invariant) ----
    float w1r[64];                            // w1r[j*8+k] = w1[j, dbase+k]
#pragma unroll
    for (int j = 0; j < HID; ++j)
        load8(&w1r[j * 8], w1 + j * DIM + dbase);

    float w2r[64];                            // w2r[k*8+j] = w2[dbase+k, j]
#pragma unroll
    for (int k = 0; k < 8; ++k)
        load8(&w2r[k * 8], w2 + (dbase + k) * HID);

    float gm[8], bt[8], b2r[8];
    load8(gm,  gamma + dbase);
    load8(bt,  beta  + dbase);
    load8(b2r, b2    + dbase);
    const float b1own = b1[lane & 7];

    // ---- prefetch first row ----
    float xv[8];
    load8(xv, x + (size_t)r0 * DIM + dbase);

    for (int r = r0; r < r1; ++r) {
        // prefetch next row's x early (hide HBM latency under compute)
        float xn[8];
        if (r + 1 < r1) load8(xn, x + (size_t)(r + 1) * DIM + dbase);

        // ---- LayerNorm stats: wave-wide sum / sumsq ----
        float s = 0.f, q = 0.f;
#pragma unroll
        for (int k = 0; k < 8; ++k) { s += xv[k]; q = fmaf(xv[k], xv[k], q); }
#pragma unroll
        for (int m = 1; m < 64; m <<= 1) {
            s += __shfl_xor(s, m, 64);
            q += __shfl_xor(q, m, 64);
        }
        const float mu  = s * (1.0f / DIM);
        const float var = q * (1.0f / DIM) - mu * mu;
        const float rs  = rsqrtf(var + LN_EPS);

        float y[8];
#pragma unroll
        for (int k = 0; k < 8; ++k)
            y[k] = fmaf((xv[k] - mu) * rs, gm[k], bt[k]);

        // ---- h[j] = sum_d y[d] * w1[j,d] : per-lane partials ----
        float ph[8] = {0.f, 0.f, 0.f, 0.f, 0.f, 0.f, 0.f, 0.f};
#pragma unroll
        for (int j = 0; j < HID; ++j)
#pragma unroll
            for (int k = 0; k < 8; ++k)
                ph[j] = fmaf(y[k], w1r[j * 8 + k], ph[j]);

        // reduce within 8-lane groups (xor 1,2,4) on all 8 partials
#pragma unroll
        for (int m = 1; m < 8; m <<= 1)
#pragma unroll
            for (int j = 0; j < HID; ++j)
                ph[j] += __shfl_xor(ph[j], m, 64);

        // lane picks partial for h-index (lane&7)  (static accesses only)
        const int lj = lane & 7;
        float sel = ph[0];
        sel = (lj == 1) ? ph[1] : sel;
        sel = (lj == 2) ? ph[2] : sel;
        sel = (lj == 3) ? ph[3] : sel;
        sel = (lj == 4) ? ph[4] : sel;
        sel = (lj == 5) ? ph[5] : sel;
        sel = (lj == 6) ? ph[6] : sel;
        sel = (lj == 7) ? ph[7] : sel;

        // reduce across the eight 8-lane groups (xor 8,16,32)
#pragma unroll
        for (int m = 8; m < 64; m <<= 1)
            sel += __shfl_xor(sel, m, 64);

        // exactly one erf per lane for the hidden GELU
        const float hact = gelu_exact(sel + b1own);

        // broadcast activated h[0..7] (lane j holds h[j] for j<8)
        float hj[8];
#pragma unroll
        for (int j = 0; j < HID; ++j)
            hj[j] = __shfl(hact, j, 64);

        // ---- o[d] = gelu(sum_j h[j]*w2[d,j] + b2[d]) + x[d] ----
        float ov[8];
#pragma unroll
        for (int k = 0; k < 8; ++k) {
            float o = b2r[k];
#pragma unroll
            for (int j = 0; j < HID; ++j)
                o = fmaf(hj[j], w2r[k * 8 + j], o);
            ov[k] = gelu_exact(o) + xv[k];
        }

        // ---- coalesced store ----
        float4* po = reinterpret_cast<float4*>(out + (size_t)r * DIM + dbase);
        po[0] = make_float4(ov[0], ov[1], ov[2], ov[3]);
        po[1] = make_float4(ov[4], ov[5], ov[6], ov[7]);

        // rotate prefetched row in
#pragma unroll
        for (int k = 0; k < 8; ++k) xv[k] = xn[k];
    }
}

extern "C" void kernel_launch(void* const* d_in, const int* in_sizes, int n_in,
                              void* d_out, int out_size, void* d_ws, size_t ws_size,
                              hipStream_t stream) {
    const float* x     = (const float*)d_in[0];
    const float* w1    = (const float*)d_in[1];
    const float* b1    = (const float*)d_in[2];
    const float* w2    = (const float*)d_in[3];
    const float* b2    = (const float*)d_in[4];
    const float* gamma = (const float*)d_in[5];
    const float* beta  = (const float*)d_in[6];
    float* out = (float*)d_out;

    const int nrows = in_sizes[0] / DIM;          // 128*1024 = 131072
    const int blocks = 2048;                      // 4 waves each
    const int total_waves = blocks * 4;
    const int rows_per_wave = (nrows + total_waves - 1) / total_waves;

    mlp_fused_kernel<<<blocks, 256, 0, stream>>>(
        x, w1, b1, w2, b2, gamma, beta, out, nrows, rows_per_wave);
}

// Round 3
// 136.062 us; speedup vs baseline: 1.1058x; 1.1058x over previous
//
#include <hip/hip_runtime.h>
#include <math.h>

#define DIM 512
#define HID 8
#define LN_EPS 1e-5f

typedef float f32x4 __attribute__((ext_vector_type(4)));

// tanh-GELU via hardware exp2/rcp:
// gelu(x) ~= 0.5x(1+tanh(0.79788456(x+0.044715x^3))) = x*(1 - 1/(e^{2a}+1))
// 2a*log2(e) = K * x * (1 + 0.044715 x^2),  K = 2*0.79788456*1.44269504
__device__ __forceinline__ float gelu_fast(float v) {
    const float C = 0.044715f;
    const float K = 2.30258819f; // 2*0.7978845608*1.4426950408
    float v2 = v * v;
    float u  = fmaf(C, v2, 1.0f);     // 1 + C v^2
    float t  = v * u;                  // v + C v^3
    float e  = __builtin_amdgcn_exp2f(K * t);  // 2^(K t) = e^{2a}
    float r  = __builtin_amdgcn_rcpf(e + 1.0f);
    return fmaf(-v, r, v);             // v*(1-r)
}

__device__ __forceinline__ void load8(float* dst, const float* __restrict__ src) {
    const f32x4* p = reinterpret_cast<const f32x4*>(src);
    f32x4 a = p[0];
    f32x4 b = p[1];
    dst[0] = a.x; dst[1] = a.y; dst[2] = a.z; dst[3] = a.w;
    dst[4] = b.x; dst[5] = b.y; dst[6] = b.z; dst[7] = b.w;
}

__global__ __launch_bounds__(256, 2)
void mlp_fused_kernel(const float* __restrict__ x,
                      const float* __restrict__ w1,
                      const float* __restrict__ b1,
                      const float* __restrict__ w2,
                      const float* __restrict__ b2,
                      const float* __restrict__ gamma,
                      const float* __restrict__ beta,
                      float* __restrict__ out,
                      int nrows, int rows_per_wave) {
    const int lane  = threadIdx.x & 63;
    const int widx  = threadIdx.x >> 6;
    const int wgid  = blockIdx.x * 4 + widx;
    const int dbase = lane * 8;              // this lane owns d = dbase..dbase+7
    const int lj    = lane & 7;

    const int r0 = wgid * rows_per_wave;
    if (r0 >= nrows) return;
    int r1 = r0 + rows_per_wave;
    if (r1 > nrows) r1 = nrows;

    // ---- hoist all weights/params into registers (row-invariant) ----
    float w1r[64];                            // w1r[j*8+k] = w1[j, dbase+k]
#pragma unroll
    for (int j = 0; j < HID; ++j)
        load8(&w1r[j * 8], w1 + j * DIM + dbase);

    // w2p[k*8+t] = w2[dbase+k, (lj^t)]  -- XOR-permuted so the doubling
    // broadcast's lane-dependent order matches directly.
    float w2p[64];
#pragma unroll
    for (int k = 0; k < 8; ++k)
#pragma unroll
        for (int t = 0; t < 8; ++t)
            w2p[k * 8 + t] = w2[(size_t)(dbase + k) * HID + (lj ^ t)];

    float gm[8], bt[8], b2r[8];
    load8(gm,  gamma + dbase);
    load8(bt,  beta  + dbase);
    load8(b2r, b2    + dbase);
    const float b1own = b1[lj];

    // ---- pin row-invariant state in VGPRs: forbid remat/re-load in loop ----
#pragma unroll
    for (int i = 0; i < 64; ++i) asm volatile("" : "+v"(w1r[i]));
#pragma unroll
    for (int i = 0; i < 64; ++i) asm volatile("" : "+v"(w2p[i]));
#pragma unroll
    for (int i = 0; i < 8; ++i)  asm volatile("" : "+v"(gm[i]));
#pragma unroll
    for (int i = 0; i < 8; ++i)  asm volatile("" : "+v"(bt[i]));
#pragma unroll
    for (int i = 0; i < 8; ++i)  asm volatile("" : "+v"(b2r[i]));

    // ---- prefetch first row ----
    float xv[8];
    load8(xv, x + (size_t)r0 * DIM + dbase);

    for (int r = r0; r < r1; ++r) {
        // prefetch next row early (hide HBM latency under compute)
        float xn[8];
        const bool more = (r + 1 < r1);
        if (more) load8(xn, x + (size_t)(r + 1) * DIM + dbase);

        // ---- LayerNorm stats: packed parity butterfly (7 shuffles) ----
        float s = 0.f, q = 0.f;
#pragma unroll
        for (int k = 0; k < 8; ++k) { s += xv[k]; q = fmaf(xv[k], xv[k], q); }
        float c  = (lane & 1) ? q : s;
        float o1 = (lane & 1) ? s : q;
        c += __shfl_xor(o1, 1, 64);
#pragma unroll
        for (int m = 2; m < 64; m <<= 1) c += __shfl_xor(c, m, 64);
        float d1 = __shfl_xor(c, 1, 64);
        const float stot = (lane & 1) ? d1 : c;
        const float qtot = (lane & 1) ? c : d1;
        const float mu  = stot * (1.0f / DIM);
        const float var = qtot * (1.0f / DIM) - mu * mu;
        const float rs  = rsqrtf(var + LN_EPS);

        float y[8];
#pragma unroll
        for (int k = 0; k < 8; ++k)
            y[k] = fmaf((xv[k] - mu) * rs, gm[k], bt[k]);

        // ---- h[j] partials: 64 FMA ----
        float ph[8] = {0.f, 0.f, 0.f, 0.f, 0.f, 0.f, 0.f, 0.f};
#pragma unroll
        for (int j = 0; j < HID; ++j)
#pragma unroll
            for (int k = 0; k < 8; ++k)
                ph[j] = fmaf(y[k], w1r[j * 8 + k], ph[j]);

        // ---- pair-trick reduce within 8-lane group (7 shuffles):
        //      lane ends holding full group-partial of h[lane&7]
#pragma unroll
        for (int jj = 0; jj < 4; ++jj) {
            float a = ph[2 * jj], b = ph[2 * jj + 1];
            float mine = (lane & 1) ? b : a;
            float oth  = (lane & 1) ? a : b;
            ph[jj] = mine + __shfl_xor(oth, 1, 64);
        }
#pragma unroll
        for (int jj = 0; jj < 2; ++jj) {
            float a = ph[2 * jj], b = ph[2 * jj + 1];
            float mine = (lane & 2) ? b : a;
            float oth  = (lane & 2) ? a : b;
            ph[jj] = mine + __shfl_xor(oth, 2, 64);
        }
        float hsum;
        {
            float a = ph[0], b = ph[1];
            float mine = (lane & 4) ? b : a;
            float oth  = (lane & 4) ? a : b;
            hsum = mine + __shfl_xor(oth, 4, 64);
        }
        // cross-group sum (3 shuffles): h[lane&7] complete over 64 lanes
        hsum += __shfl_xor(hsum, 8, 64);
        hsum += __shfl_xor(hsum, 16, 64);
        hsum += __shfl_xor(hsum, 32, 64);

        // one fast GELU per lane for the hidden activation
        const float hact = gelu_fast(hsum + b1own);

        // ---- doubling broadcast (7 shuffles): hj[t] = h[(lane^t)&7] ----
        float hj[8];
        hj[0] = hact;
        hj[1] = __shfl_xor(hj[0], 1, 64);
        hj[2] = __shfl_xor(hj[0], 2, 64);
        hj[3] = __shfl_xor(hj[1], 2, 64);
        hj[4] = __shfl_xor(hj[0], 4, 64);
        hj[5] = __shfl_xor(hj[1], 4, 64);
        hj[6] = __shfl_xor(hj[2], 4, 64);
        hj[7] = __shfl_xor(hj[3], 4, 64);

        // ---- o[d] = gelu(sum_t hj[t]*w2p[d,t] + b2[d]) + x[d] ----
        float ov[8];
#pragma unroll
        for (int k = 0; k < 8; ++k) {
            float o = b2r[k];
#pragma unroll
            for (int t = 0; t < 8; ++t)
                o = fmaf(hj[t], w2p[k * 8 + t], o);
            ov[k] = gelu_fast(o) + xv[k];
        }

        // ---- nontemporal coalesced store (don't evict x from L3) ----
        float* po = out + (size_t)r * DIM + dbase;
        f32x4 v0 = {ov[0], ov[1], ov[2], ov[3]};
        f32x4 v1 = {ov[4], ov[5], ov[6], ov[7]};
        __builtin_nontemporal_store(v0, reinterpret_cast<f32x4*>(po));
        __builtin_nontemporal_store(v1, reinterpret_cast<f32x4*>(po) + 1);

        if (more) {
#pragma unroll
            for (int k = 0; k < 8; ++k) xv[k] = xn[k];
        }
    }
}

extern "C" void kernel_launch(void* const* d_in, const int* in_sizes, int n_in,
                              void* d_out, int out_size, void* d_ws, size_t ws_size,
                              hipStream_t stream) {
    const float* x     = (const float*)d_in[0];
    const float* w1    = (const float*)d_in[1];
    const float* b1    = (const float*)d_in[2];
    const float* w2    = (const float*)d_in[3];
    const float* b2    = (const float*)d_in[4];
    const float* gamma = (const float*)d_in[5];
    const float* beta  = (const float*)d_in[6];
    float* out = (float*)d_out;

    const int nrows = in_sizes[0] / DIM;          // 128*1024 = 131072
    const int blocks = 2048;                      // 4 waves each
    const int total_waves = blocks * 4;
    const int rows_per_wave = (nrows + total_waves - 1) / total_waves;

    mlp_fused_kernel<<<blocks, 256, 0, stream>>>(
        x, w1, b1, w2, b2, gamma, beta, out, nrows, rows_per_wave);
}

// Round 4
// 118.848 us; speedup vs baseline: 1.2660x; 1.1448x over previous
//
#include <hip/hip_runtime.h>
#include <math.h>

#define DIM 512
#define HID 8
#define LN_EPS 1e-5f

typedef float f32x4 __attribute__((ext_vector_type(4)));

// ---- DPP cross-lane helpers (VALU-speed, no LDS) ----
#define DPP_XOR1 0xB1   // quad_perm [1,0,3,2]  : true xor1
#define DPP_XOR2 0x4E   // quad_perm [2,3,0,1]  : true xor2
#define DPP_HM   0x141  // row_half_mirror (i^7 in 8) : ==xor4 once 4-uniform
#define DPP_ROR8 0x128  // (i+8)&15 == i^8      : true xor8 within 16
#define DPP_ROR4 0x124  // (i+4)&15 : ==xor4 (mod 8) on 8-periodic data

template <int CTRL>
__device__ __forceinline__ float dpp_movf(float v) {
    int r = __builtin_amdgcn_update_dpp(0, __builtin_bit_cast(int, v),
                                        CTRL, 0xF, 0xF, true);
    return __builtin_bit_cast(float, r);
}
template <int CTRL>
__device__ __forceinline__ float dpp_addf(float v) {
    return v + dpp_movf<CTRL>(v);
}
__device__ __forceinline__ float readlanef(float v, int lane) {
    return __builtin_bit_cast(float,
        __builtin_amdgcn_readlane(__builtin_bit_cast(int, v), lane));
}

// tanh-GELU via hardware exp2/rcp (abs err ~1e-3, threshold is 0.166)
__device__ __forceinline__ float gelu_fast(float v) {
    const float C = 0.044715f;
    const float K = 2.30258819f; // 2*0.7978845608*log2(e)
    float v2 = v * v;
    float t  = v * fmaf(C, v2, 1.0f);
    float e  = __builtin_amdgcn_exp2f(K * t);
    float r  = __builtin_amdgcn_rcpf(e + 1.0f);
    return fmaf(-v, r, v);
}

__device__ __forceinline__ void load8(float* dst, const float* __restrict__ src) {
    const f32x4* p = reinterpret_cast<const f32x4*>(src);
    f32x4 a = p[0];
    f32x4 b = p[1];
    dst[0] = a.x; dst[1] = a.y; dst[2] = a.z; dst[3] = a.w;
    dst[4] = b.x; dst[5] = b.y; dst[6] = b.z; dst[7] = b.w;
}

__global__ __launch_bounds__(256, 2)
void mlp_fused_kernel(const float* __restrict__ x,
                      const float* __restrict__ w1,
                      const float* __restrict__ b1,
                      const float* __restrict__ w2,
                      const float* __restrict__ b2,
                      const float* __restrict__ gamma,
                      const float* __restrict__ beta,
                      float* __restrict__ out,
                      int nrows, int rows_per_wave) {
    const int lane  = threadIdx.x & 63;
    const int widx  = threadIdx.x >> 6;
    const int wgid  = blockIdx.x * 4 + widx;
    const int dbase = lane * 8;
    const int lj    = lane & 7;

    const int r0 = wgid * rows_per_wave;
    if (r0 >= nrows) return;
    int r1 = r0 + rows_per_wave;
    if (r1 > nrows) r1 = nrows;

    // ---- hoist all row-invariant weights/params ----
    float w1r[64];                             // w1r[j*8+k] = w1[j, dbase+k]
#pragma unroll
    for (int j = 0; j < HID; ++j)
        load8(&w1r[j * 8], w1 + j * DIM + dbase);

    float w2p[64];                             // w2p[k*8+t] = w2[dbase+k, lj^t]
#pragma unroll
    for (int k = 0; k < 8; ++k)
#pragma unroll
        for (int t = 0; t < 8; ++t)
            w2p[k * 8 + t] = w2[(size_t)(dbase + k) * HID + (lj ^ t)];

    float gm[8], bt[8], b2r[8];
    load8(gm,  gamma + dbase);
    load8(bt,  beta  + dbase);
    load8(b2r, b2    + dbase);
    const float b1own = b1[lj];

    // ---- prefetch first row ----
    float xv[8];
    load8(xv, x + (size_t)r0 * DIM + dbase);

    for (int r = r0; r < r1; ++r) {
        // Pin invariants INSIDE the loop: loop-carried "+v" deps force true
        // VGPR residency (a one-shot pin lets the allocator spill them).
#pragma unroll
        for (int i = 0; i < 64; ++i) asm volatile("" : "+v"(w1r[i]));
#pragma unroll
        for (int i = 0; i < 64; ++i) asm volatile("" : "+v"(w2p[i]));
#pragma unroll
        for (int i = 0; i < 8; ++i) {
            asm volatile("" : "+v"(gm[i]));
            asm volatile("" : "+v"(bt[i]));
            asm volatile("" : "+v"(b2r[i]));
        }

        // prefetch next row (clamped; wave-uniform)
        float xn[8];
        const int rn = (r + 1 < r1) ? (r + 1) : r;
        load8(xn, x + (size_t)rn * DIM + dbase);

        // ---- LayerNorm stats: DPP tree + readlane (zero DS ops) ----
        float s = 0.f, q = 0.f;
#pragma unroll
        for (int k = 0; k < 8; ++k) { s += xv[k]; q = fmaf(xv[k], xv[k], q); }
        s = dpp_addf<DPP_XOR1>(s); q = dpp_addf<DPP_XOR1>(q);
        s = dpp_addf<DPP_XOR2>(s); q = dpp_addf<DPP_XOR2>(q);
        s = dpp_addf<DPP_HM  >(s); q = dpp_addf<DPP_HM  >(q);
        s = dpp_addf<DPP_ROR8>(s); q = dpp_addf<DPP_ROR8>(q);
        const float stot = (readlanef(s, 0) + readlanef(s, 16))
                         + (readlanef(s, 32) + readlanef(s, 48));
        const float qtot = (readlanef(q, 0) + readlanef(q, 16))
                         + (readlanef(q, 32) + readlanef(q, 48));
        const float mu  = stot * (1.0f / DIM);
        const float var = qtot * (1.0f / DIM) - mu * mu;
        const float rs  = rsqrtf(var + LN_EPS);

        float y[8];
#pragma unroll
        for (int k = 0; k < 8; ++k)
            y[k] = fmaf((xv[k] - mu) * rs, gm[k], bt[k]);

        // ---- h partials: 64 FMA ----
        float ph[8] = {0.f, 0.f, 0.f, 0.f, 0.f, 0.f, 0.f, 0.f};
#pragma unroll
        for (int j = 0; j < HID; ++j)
#pragma unroll
            for (int k = 0; k < 8; ++k)
                ph[j] = fmaf(y[k], w1r[j * 8 + k], ph[j]);

        // in-8-group butterfly: 3 DPP levels, ILP across the 8 partials
#pragma unroll
        for (int j = 0; j < HID; ++j) ph[j] = dpp_addf<DPP_XOR1>(ph[j]);
#pragma unroll
        for (int j = 0; j < HID; ++j) ph[j] = dpp_addf<DPP_XOR2>(ph[j]);
#pragma unroll
        for (int j = 0; j < HID; ++j) ph[j] = dpp_addf<DPP_HM>(ph[j]);

        // lane takes h[lane&7]'s group-partial
        float sel = ph[0];
        sel = (lj == 1) ? ph[1] : sel;
        sel = (lj == 2) ? ph[2] : sel;
        sel = (lj == 3) ? ph[3] : sel;
        sel = (lj == 4) ? ph[4] : sel;
        sel = (lj == 5) ? ph[5] : sel;
        sel = (lj == 6) ? ph[6] : sel;
        sel = (lj == 7) ? ph[7] : sel;

        // cross-group: xor8 via DPP; xor16/32 via the only 2 DS ops per row
        sel = dpp_addf<DPP_ROR8>(sel);
        sel += __shfl_xor(sel, 16, 64);
        sel += __shfl_xor(sel, 32, 64);

        const float hact = gelu_fast(sel + b1own);   // lane holds H[lane&7]

        // ---- broadcast via pure DPP: hj[t] = H[(lane^t)&7] ----
        float hj[8];
        hj[0] = hact;
        hj[1] = dpp_movf<DPP_XOR1>(hj[0]);
        hj[2] = dpp_movf<DPP_XOR2>(hj[0]);
        hj[3] = dpp_movf<DPP_XOR2>(hj[1]);
        hj[4] = dpp_movf<DPP_ROR4>(hj[0]);
        hj[5] = dpp_movf<DPP_ROR4>(hj[1]);
        hj[6] = dpp_movf<DPP_ROR4>(hj[2]);
        hj[7] = dpp_movf<DPP_ROR4>(hj[3]);

        // ---- o[d] = gelu(sum_t hj[t]*w2p[d,t] + b2[d]) + x[d] ----
        float ov[8];
#pragma unroll
        for (int k = 0; k < 8; ++k) {
            float o = b2r[k];
#pragma unroll
            for (int t = 0; t < 8; ++t)
                o = fmaf(hj[t], w2p[k * 8 + t], o);
            ov[k] = gelu_fast(o) + xv[k];
        }

        // ---- nontemporal coalesced store ----
        float* po = out + (size_t)r * DIM + dbase;
        f32x4 v0 = {ov[0], ov[1], ov[2], ov[3]};
        f32x4 v1 = {ov[4], ov[5], ov[6], ov[7]};
        __builtin_nontemporal_store(v0, reinterpret_cast<f32x4*>(po));
        __builtin_nontemporal_store(v1, reinterpret_cast<f32x4*>(po) + 1);

#pragma unroll
        for (int k = 0; k < 8; ++k) xv[k] = xn[k];
    }
}

extern "C" void kernel_launch(void* const* d_in, const int* in_sizes, int n_in,
                              void* d_out, int out_size, void* d_ws, size_t ws_size,
                              hipStream_t stream) {
    const float* x     = (const float*)d_in[0];
    const float* w1    = (const float*)d_in[1];
    const float* b1    = (const float*)d_in[2];
    const float* w2    = (const float*)d_in[3];
    const float* b2    = (const float*)d_in[4];
    const float* gamma = (const float*)d_in[5];
    const float* beta  = (const float*)d_in[6];
    float* out = (float*)d_out;

    const int nrows = in_sizes[0] / DIM;          // 131072
    const int blocks = 2048;                      // 4 waves each -> 8192 waves
    const int total_waves = blocks * 4;
    const int rows_per_wave = (nrows + total_waves - 1) / total_waves;

    mlp_fused_kernel<<<blocks, 256, 0, stream>>>(
        x, w1, b1, w2, b2, gamma, beta, out, nrows, rows_per_wave);
}